// Round 1
// baseline (688.433 us; speedup 1.0000x reference)
//
#include <hip/hip_runtime.h>
#include <math.h>

#define TOK 4096
#define D 1024
#define DFF 4096
#define NE 8
#define CAP 4096

typedef _Float16 half4v __attribute__((ext_vector_type(4)));
typedef _Float16 half8v __attribute__((ext_vector_type(8)));
typedef float f32x4 __attribute__((ext_vector_type(4)));

// ---------------- ws layout (bytes) ----------------
// [0,64)        counts[8] (zeroed each call)
// [64,128)      offs[9]
// [128,192)     npad[8]
// [1024,33792)  tk_e[TOK][2] int
// [33792,66560) tk_w[TOK][2] float
// [66560,197632)  tok_list[8][4096] int
// [197632,328704) tok_w[8][4096] float
// [1MB, 1MB+75.5MB) H^T fp16 (per-expert [DFF][npad_e] at slot offset offs[e])

__global__ void k_gate(const float* __restrict__ x, const float* __restrict__ Wg,
                       const float* __restrict__ bg, int* __restrict__ counts,
                       int* __restrict__ tk_e, float* __restrict__ tk_w,
                       int* __restrict__ tok_list, float* __restrict__ tok_w) {
    int t = blockIdx.x * 4 + (threadIdx.x >> 6);
    int lane = threadIdx.x & 63;
    const float* xr = x + (size_t)t * D;
    float a[NE];
#pragma unroll
    for (int e = 0; e < NE; ++e) a[e] = 0.f;
    for (int d = lane; d < D; d += 64) {
        float xv = xr[d];
        const float4 w0 = *(const float4*)(Wg + d * NE);
        const float4 w1 = *(const float4*)(Wg + d * NE + 4);
        a[0] += xv * w0.x; a[1] += xv * w0.y; a[2] += xv * w0.z; a[3] += xv * w0.w;
        a[4] += xv * w1.x; a[5] += xv * w1.y; a[6] += xv * w1.z; a[7] += xv * w1.w;
    }
#pragma unroll
    for (int m = 1; m < 64; m <<= 1) {
#pragma unroll
        for (int e = 0; e < NE; ++e) a[e] += __shfl_xor(a[e], m, 64);
    }
    if (lane == 0) {
#pragma unroll
        for (int e = 0; e < NE; ++e) a[e] += bg[e];
        int i0 = 0;
#pragma unroll
        for (int e = 1; e < NE; ++e) if (a[e] > a[i0]) i0 = e;
        int i1 = (i0 == 0) ? 1 : 0;
#pragma unroll
        for (int e = 0; e < NE; ++e) if (e != i0 && a[e] > a[i1]) i1 = e;
        float ee = expf(a[i1] - a[i0]);
        float w0 = 1.f / (1.f + ee);
        float w1 = ee / (1.f + ee);
        tk_e[t * 2] = i0; tk_e[t * 2 + 1] = i1;
        tk_w[t * 2] = w0; tk_w[t * 2 + 1] = w1;
        int p0 = atomicAdd(&counts[i0], 1);
        tok_list[i0 * CAP + p0] = t; tok_w[i0 * CAP + p0] = w0;
        int p1 = atomicAdd(&counts[i1], 1);
        tok_list[i1 * CAP + p1] = t; tok_w[i1 * CAP + p1] = w1;
    }
}

__global__ void k_prep(const int* __restrict__ counts, int* __restrict__ offs,
                       int* __restrict__ npad) {
    int o = 0;
    for (int e = 0; e < NE; ++e) {
        offs[e] = o;
        int np = (counts[e] + 127) & ~127;
        npad[e] = np;
        o += np;
    }
    offs[NE] = o;
}

__global__ void k_init(const int* __restrict__ tk_e, const float* __restrict__ tk_w,
                       const float* __restrict__ b2, float* __restrict__ out) {
    int idx = blockIdx.x * blockDim.x + threadIdx.x;  // over TOK*D/4
    int t = idx >> 8;
    int dq = (idx & 255) * 4;
    int e0 = tk_e[t * 2], e1 = tk_e[t * 2 + 1];
    float w0 = tk_w[t * 2], w1 = tk_w[t * 2 + 1];
    float4 v0 = *(const float4*)(b2 + e0 * D + dq);
    float4 v1 = *(const float4*)(b2 + e1 * D + dq);
    float4 r;
    r.x = w0 * v0.x + w1 * v1.x;
    r.y = w0 * v0.y + w1 * v1.y;
    r.z = w0 * v0.z + w1 * v1.z;
    r.w = w0 * v0.w + w1 * v1.w;
    *(float4*)(out + (size_t)idx * 4) = r;
}

// GEMM1: H^T[e] = gelu(X_gathered @ W1[e] + b1[e])^T, fp16
__global__ __launch_bounds__(256, 2)
void k_ffn1(const float* __restrict__ x, const float* __restrict__ W1,
            const float* __restrict__ b1, const int* __restrict__ counts,
            const int* __restrict__ offs, const int* __restrict__ npad,
            const int* __restrict__ tok_list, _Float16* __restrict__ H) {
    int e = blockIdx.z;
    int n_e = counts[e];
    int by = blockIdx.y;
    if (by * 128 >= n_e) return;
    int bx = blockIdx.x;
    int colb = bx * 128;

    __shared__ __align__(16) _Float16 As[128 * 64];     // rows of 64 fp16, XOR-swizzled 32B units
    __shared__ __align__(16) _Float16 Bs[8 * 128 * 8];  // fragment order [kg][n][8]
    __shared__ int s_tok[128];

    int tid = threadIdx.x;
    int lane = tid & 63, wid = tid >> 6;
    int wm = (wid >> 1) * 64, wn = (wid & 1) * 64;
    int g = lane >> 4, cl = lane & 15;

    if (tid < 128) {
        int m = by * 128 + tid;
        s_tok[tid] = tok_list[e * CAP + (m < n_e ? m : 0)];
    }

    f32x4 acc[4][4];
#pragma unroll
    for (int i = 0; i < 4; ++i)
#pragma unroll
        for (int j = 0; j < 4; ++j) { acc[i][j][0] = 0.f; acc[i][j][1] = 0.f; acc[i][j][2] = 0.f; acc[i][j][3] = 0.f; }

    const float* W1e = W1 + (size_t)e * D * DFF;

    for (int kt = 0; kt < D; kt += 64) {
        __syncthreads();
        // stage A: gathered x rows fp32 -> fp16, swizzle 32B unit u ^= (row&7)
#pragma unroll
        for (int p = 0; p < 8; ++p) {
            int unit = tid + p * 256;
            int r = unit >> 4, c = unit & 15;
            float4 v = *(const float4*)(x + (size_t)s_tok[r] * D + kt + c * 4);
            half4v h;
            h[0] = (_Float16)v.x; h[1] = (_Float16)v.y; h[2] = (_Float16)v.z; h[3] = (_Float16)v.w;
            int u = (c >> 1) ^ (r & 7);
            *(half4v*)(&As[r * 64 + u * 8 + (c & 1) * 4]) = h;
        }
        // stage B: W1 column-loads fp32 -> fp16, fragment order
#pragma unroll
        for (int p = 0; p < 4; ++p) {
            int n = (tid & 63) + (p & 1) * 64;
            int kg = (tid >> 6) * 2 + (p >> 1);
            const float* src = W1e + (size_t)(kt + kg * 8) * DFF + colb + n;
            half8v h;
#pragma unroll
            for (int j = 0; j < 8; ++j) h[j] = (_Float16)src[(size_t)j * DFF];
            *(half8v*)(&Bs[(kg * 128 + n) * 8]) = h;
        }
        __syncthreads();
#pragma unroll
        for (int ks = 0; ks < 2; ++ks) {
            half8v aF[4], bF[4];
#pragma unroll
            for (int fm = 0; fm < 4; ++fm) {
                int r = wm + fm * 16 + cl;
                int u = (ks * 4 + g) ^ (lane & 7);
                aF[fm] = *(half8v*)(&As[r * 64 + u * 8]);
            }
#pragma unroll
            for (int fn = 0; fn < 4; ++fn) {
                int n = wn + fn * 16 + cl;
                bF[fn] = *(half8v*)(&Bs[((ks * 4 + g) * 128 + n) * 8]);
            }
#pragma unroll
            for (int fm = 0; fm < 4; ++fm)
#pragma unroll
                for (int fn = 0; fn < 4; ++fn)
                    acc[fm][fn] = __builtin_amdgcn_mfma_f32_16x16x32_f16(aF[fm], bF[fn], acc[fm][fn], 0, 0, 0);
        }
    }

    int np = npad[e];
    _Float16* He = H + (size_t)offs[e] * DFF;  // He^T[k][m] at He + k*np + m
#pragma unroll
    for (int fn = 0; fn < 4; ++fn) {
        int gcol = colb + wn + fn * 16 + cl;
        float bias = b1[e * DFF + gcol];
#pragma unroll
        for (int fm = 0; fm < 4; ++fm) {
            int row0 = by * 128 + wm + fm * 16 + g * 4;
            if (row0 >= n_e) continue;
            half4v hv;
#pragma unroll
            for (int j = 0; j < 4; ++j) {
                float v = acc[fm][fn][j] + bias;
                v = 0.5f * v * (1.f + erff(v * 0.70710678118f));
                hv[j] = (_Float16)v;
            }
            if (row0 + 3 < n_e) {
                *(half4v*)(&He[(size_t)gcol * np + row0]) = hv;
            } else {
#pragma unroll
                for (int j = 0; j < 4; ++j)
                    if (row0 + j < n_e) He[(size_t)gcol * np + row0 + j] = hv[j];
            }
        }
    }
}

// GEMM2: out[tok] += w * (H_e @ W2[e]) via atomics
__global__ __launch_bounds__(256, 2)
void k_ffn2(const _Float16* __restrict__ H, const float* __restrict__ W2,
            const int* __restrict__ counts, const int* __restrict__ offs,
            const int* __restrict__ npad, const int* __restrict__ tok_list,
            const float* __restrict__ tok_w, float* __restrict__ out) {
    int e = blockIdx.z;
    int n_e = counts[e];
    int by = blockIdx.y;
    if (by * 128 >= n_e) return;
    int bx = blockIdx.x;
    int colb = bx * 128;

    __shared__ __align__(16) _Float16 As[8 * 128 * 8];  // fragment order [kg][m][8]
    __shared__ __align__(16) _Float16 Bs[8 * 128 * 8];  // fragment order [kg][n][8]
    __shared__ int s_tok[128];
    __shared__ float s_w[128];

    int tid = threadIdx.x;
    int lane = tid & 63, wid = tid >> 6;
    int wm = (wid >> 1) * 64, wn = (wid & 1) * 64;
    int g = lane >> 4, cl = lane & 15;

    if (tid < 128) {
        int m = by * 128 + tid;
        bool v = m < n_e;
        s_tok[tid] = v ? tok_list[e * CAP + m] : 0;
        s_w[tid] = v ? tok_w[e * CAP + m] : 0.f;
    }

    f32x4 acc[4][4];
#pragma unroll
    for (int i = 0; i < 4; ++i)
#pragma unroll
        for (int j = 0; j < 4; ++j) { acc[i][j][0] = 0.f; acc[i][j][1] = 0.f; acc[i][j][2] = 0.f; acc[i][j][3] = 0.f; }

    int np = npad[e];
    const _Float16* He = H + (size_t)offs[e] * DFF;
    const float* W2e = W2 + (size_t)e * DFF * D;

    for (int kt = 0; kt < DFF; kt += 64) {
        __syncthreads();
#pragma unroll
        for (int p = 0; p < 4; ++p) {
            int m = (tid & 63) + (p & 1) * 64;
            int kg = (tid >> 6) * 2 + (p >> 1);
            const _Float16* src = He + (size_t)(kt + kg * 8) * np + by * 128 + m;
            half8v h;
#pragma unroll
            for (int j = 0; j < 8; ++j) h[j] = src[(size_t)j * np];
            *(half8v*)(&As[(kg * 128 + m) * 8]) = h;
        }
#pragma unroll
        for (int p = 0; p < 4; ++p) {
            int n = (tid & 63) + (p & 1) * 64;
            int kg = (tid >> 6) * 2 + (p >> 1);
            const float* src = W2e + (size_t)(kt + kg * 8) * D + colb + n;
            half8v h;
#pragma unroll
            for (int j = 0; j < 8; ++j) h[j] = (_Float16)src[(size_t)j * D];
            *(half8v*)(&Bs[(kg * 128 + n) * 8]) = h;
        }
        __syncthreads();
#pragma unroll
        for (int ks = 0; ks < 2; ++ks) {
            half8v aF[4], bF[4];
#pragma unroll
            for (int fm = 0; fm < 4; ++fm)
                aF[fm] = *(half8v*)(&As[((ks * 4 + g) * 128 + wm + fm * 16 + cl) * 8]);
#pragma unroll
            for (int fn = 0; fn < 4; ++fn)
                bF[fn] = *(half8v*)(&Bs[((ks * 4 + g) * 128 + wn + fn * 16 + cl) * 8]);
#pragma unroll
            for (int fm = 0; fm < 4; ++fm)
#pragma unroll
                for (int fn = 0; fn < 4; ++fn)
                    acc[fm][fn] = __builtin_amdgcn_mfma_f32_16x16x32_f16(aF[fm], bF[fn], acc[fm][fn], 0, 0, 0);
        }
    }

#pragma unroll
    for (int fm = 0; fm < 4; ++fm) {
#pragma unroll
        for (int j = 0; j < 4; ++j) {
            int ml = wm + fm * 16 + g * 4 + j;
            if (by * 128 + ml >= n_e) continue;
            int t = s_tok[ml];
            float w = s_w[ml];
            float* orow = out + (size_t)t * D + colb + wn;
#pragma unroll
            for (int fn = 0; fn < 4; ++fn)
                atomicAdd(orow + fn * 16 + cl, w * acc[fm][fn][j]);
        }
    }
}

extern "C" void kernel_launch(void* const* d_in, const int* in_sizes, int n_in,
                              void* d_out, int out_size, void* d_ws, size_t ws_size,
                              hipStream_t stream) {
    const float* x  = (const float*)d_in[0];
    const float* W1 = (const float*)d_in[1];
    const float* b1 = (const float*)d_in[2];
    const float* W2 = (const float*)d_in[3];
    const float* b2 = (const float*)d_in[4];
    const float* Wg = (const float*)d_in[5];
    const float* bg = (const float*)d_in[6];
    float* out = (float*)d_out;

    char* ws = (char*)d_ws;
    int*   counts   = (int*)(ws);
    int*   offs     = (int*)(ws + 64);
    int*   npad     = (int*)(ws + 128);
    int*   tk_e     = (int*)(ws + 1024);
    float* tk_w     = (float*)(ws + 1024 + 32768);
    int*   tok_list = (int*)(ws + 66560);
    float* tok_w    = (float*)(ws + 197632);
    _Float16* H     = (_Float16*)(ws + (1u << 20));

    hipMemsetAsync(counts, 0, 64, stream);
    k_gate<<<TOK / 4, 256, 0, stream>>>(x, Wg, bg, counts, tk_e, tk_w, tok_list, tok_w);
    k_prep<<<1, 1, 0, stream>>>(counts, offs, npad);
    k_init<<<(TOK * D / 4) / 256, 256, 0, stream>>>(tk_e, tk_w, b2, out);
    k_ffn1<<<dim3(DFF / 128, 32, NE), 256, 0, stream>>>(x, W1, b1, counts, offs, npad, tok_list, H);
    k_ffn2<<<dim3(D / 128, 32, NE), 256, 0, stream>>>(H, W2, counts, offs, npad, tok_list, tok_w, out);
}

// Round 2
// 439.426 us; speedup vs baseline: 1.5667x; 1.5667x over previous
//
#include <hip/hip_runtime.h>
#include <math.h>

#define TOK 4096
#define D 1024
#define DFF 4096
#define NE 8
#define CAP 4096
#define CAPTOT 9216

typedef _Float16 half4v __attribute__((ext_vector_type(4)));
typedef _Float16 half8v __attribute__((ext_vector_type(8)));
typedef float f32x4 __attribute__((ext_vector_type(4)));

#define GLOAD16(gp, lp) __builtin_amdgcn_global_load_lds( \
    (const __attribute__((address_space(1))) void*)(gp),  \
    (__attribute__((address_space(3))) void*)(lp), 16, 0, 0)

// ---------------- ws layout (bytes) ----------------
// 0        counts[8]
// 64       offs[16]
// 256      tk_e[TOK][2]      (32 KB)
// 33024    tk_w[TOK][2]      (32 KB)
// 65792    tk_pos[TOK][2]    (32 KB)
// 98560    tok_list[8][CAP]  (128 KB)
// 1 MB     x_h fp16 [TOK][D]            (8 MB)
// 10 MB    W1t fp16 [E][DFF][D]         (67 MB)   <- Y fp16 [2][CAPTOT][D] (37.7 MB) overlays after ffn1
// 75 MB+   W2t fp16 [E][D][DFF]         (67 MB)
// 140 MB+  H   fp16 [CAPTOT][DFF]       (75.5 MB)

__global__ void k_gate(const float* __restrict__ x, const float* __restrict__ Wg,
                       const float* __restrict__ bg, int* __restrict__ counts,
                       int* __restrict__ tk_e, float* __restrict__ tk_w,
                       int* __restrict__ tk_pos, int* __restrict__ tok_list) {
    int t = blockIdx.x * 4 + (threadIdx.x >> 6);
    int lane = threadIdx.x & 63;
    const float* xr = x + (size_t)t * D;
    float a[NE];
#pragma unroll
    for (int e = 0; e < NE; ++e) a[e] = 0.f;
    for (int d = lane; d < D; d += 64) {
        float xv = xr[d];
        const float4 w0 = *(const float4*)(Wg + d * NE);
        const float4 w1 = *(const float4*)(Wg + d * NE + 4);
        a[0] += xv * w0.x; a[1] += xv * w0.y; a[2] += xv * w0.z; a[3] += xv * w0.w;
        a[4] += xv * w1.x; a[5] += xv * w1.y; a[6] += xv * w1.z; a[7] += xv * w1.w;
    }
#pragma unroll
    for (int m = 1; m < 64; m <<= 1) {
#pragma unroll
        for (int e = 0; e < NE; ++e) a[e] += __shfl_xor(a[e], m, 64);
    }
    if (lane == 0) {
#pragma unroll
        for (int e = 0; e < NE; ++e) a[e] += bg[e];
        int i0 = 0;
#pragma unroll
        for (int e = 1; e < NE; ++e) if (a[e] > a[i0]) i0 = e;
        int i1 = (i0 == 0) ? 1 : 0;
#pragma unroll
        for (int e = 0; e < NE; ++e) if (e != i0 && a[e] > a[i1]) i1 = e;
        float ee = expf(a[i1] - a[i0]);
        float w0 = 1.f / (1.f + ee);
        float w1 = ee / (1.f + ee);
        tk_e[t * 2] = i0; tk_e[t * 2 + 1] = i1;
        tk_w[t * 2] = w0; tk_w[t * 2 + 1] = w1;
        int p0 = atomicAdd(&counts[i0], 1);
        tok_list[i0 * CAP + p0] = t; tk_pos[t * 2] = p0;
        int p1 = atomicAdd(&counts[i1], 1);
        tok_list[i1 * CAP + p1] = t; tk_pos[t * 2 + 1] = p1;
    }
}

__global__ void k_prep(const int* __restrict__ counts, int* __restrict__ offs) {
    int o = 0;
    for (int e = 0; e < NE; ++e) { offs[e] = o; o += (counts[e] + 127) & ~127; }
    offs[NE] = o;
}

__global__ void k_cvt_x(const float* __restrict__ x, _Float16* __restrict__ xh) {
    int idx = blockIdx.x * 256 + threadIdx.x;   // 8 els each
    const float4* s = (const float4*)x + (size_t)idx * 2;
    float4 a = s[0], b = s[1];
    half8v h;
    h[0] = (_Float16)a.x; h[1] = (_Float16)a.y; h[2] = (_Float16)a.z; h[3] = (_Float16)a.w;
    h[4] = (_Float16)b.x; h[5] = (_Float16)b.y; h[6] = (_Float16)b.z; h[7] = (_Float16)b.w;
    *(half8v*)(xh + (size_t)idx * 8) = h;
}

// transpose+convert: src fp32 [E][R][C] -> dst fp16 [E][C][R]
__global__ void k_tr(const float* __restrict__ src, _Float16* __restrict__ dst,
                     int R, int C) {
    int e = blockIdx.z;
    const float* S = src + (size_t)e * R * C;
    _Float16* T = dst + (size_t)e * C * R;
    __shared__ float tile[64][65];
    int r0 = blockIdx.y * 64, c0 = blockIdx.x * 64;
    int tid = threadIdx.x;
    int tr = tid >> 4, tc4 = (tid & 15) * 4;
#pragma unroll
    for (int i = 0; i < 4; ++i) {
        int r = i * 16 + tr;
        float4 v = *(const float4*)(S + (size_t)(r0 + r) * C + c0 + tc4);
        tile[tc4 + 0][r] = v.x;
        tile[tc4 + 1][r] = v.y;
        tile[tc4 + 2][r] = v.z;
        tile[tc4 + 3][r] = v.w;
    }
    __syncthreads();
    int wc = tid >> 2, wr = (tid & 3) * 16;
    half8v h0, h1;
#pragma unroll
    for (int j = 0; j < 8; ++j) {
        h0[j] = (_Float16)tile[wc][wr + j];
        h1[j] = (_Float16)tile[wc][wr + 8 + j];
    }
    _Float16* dr = T + (size_t)(c0 + wc) * R + r0 + wr;
    *(half8v*)dr = h0;
    *(half8v*)(dr + 8) = h1;
}

// GEMM1: H[slot][DFF] = gelu(x_gathered @ W1 + b1), A = W1t (feat-major), B = x rows
__global__ __launch_bounds__(256, 4)
void k_ffn1(const _Float16* __restrict__ xh, const _Float16* __restrict__ W1t,
            const float* __restrict__ b1, const int* __restrict__ counts,
            const int* __restrict__ offs, const int* __restrict__ tok_list,
            _Float16* __restrict__ H) {
    int e = blockIdx.z;
    int n_e = counts[e];
    int by = blockIdx.y;
    if (by * 128 >= n_e) return;
    int bx = blockIdx.x;

    __shared__ __align__(16) _Float16 As[128 * 64];
    __shared__ __align__(16) _Float16 Bs[128 * 64];
    __shared__ int s_tok[128];

    int tid = threadIdx.x, lane = tid & 63, wid = tid >> 6;
    if (tid < 128) {
        int m = by * 128 + tid;
        s_tok[tid] = tok_list[e * CAP + (m < n_e ? m : 0)];
    }
    __syncthreads();

    int srow = lane >> 3, u = lane & 7;
    int wm = (wid >> 1) * 64, wn = (wid & 1) * 64;
    int cl = lane & 15, g = lane >> 4;
    int v8 = u ^ srow;  // swizzled 16B unit (row&7 == srow)

    const _Float16* Abase = W1t + (size_t)e * DFF * D + (size_t)(bx * 128) * D;
    const _Float16* bsrc[4];
    int rbase = wid * 32 + srow;
#pragma unroll
    for (int i = 0; i < 4; ++i)
        bsrc[i] = xh + (size_t)s_tok[rbase + i * 8] * D + v8 * 8;

    f32x4 acc[4][4];
#pragma unroll
    for (int i = 0; i < 4; ++i)
#pragma unroll
        for (int j = 0; j < 4; ++j) acc[i][j] = (f32x4)0.f;

    for (int kt = 0; kt < D; kt += 64) {
#pragma unroll
        for (int i = 0; i < 4; ++i)
            GLOAD16(Abase + (size_t)(rbase + i * 8) * D + kt + v8 * 8, As + (wid * 4 + i) * 512);
#pragma unroll
        for (int i = 0; i < 4; ++i)
            GLOAD16(bsrc[i] + kt, Bs + (wid * 4 + i) * 512);
        __syncthreads();
#pragma unroll
        for (int ks = 0; ks < 2; ++ks) {
            half8v aF[4], bF[4];
            int vv = ((ks * 4 + g) ^ (cl & 7)) * 8;
#pragma unroll
            for (int fm = 0; fm < 4; ++fm)
                aF[fm] = *(const half8v*)(As + (wm + fm * 16 + cl) * 64 + vv);
#pragma unroll
            for (int fn = 0; fn < 4; ++fn)
                bF[fn] = *(const half8v*)(Bs + (wn + fn * 16 + cl) * 64 + vv);
#pragma unroll
            for (int fm = 0; fm < 4; ++fm)
#pragma unroll
                for (int fn = 0; fn < 4; ++fn)
                    acc[fm][fn] = __builtin_amdgcn_mfma_f32_16x16x32_f16(aF[fm], bF[fn], acc[fm][fn], 0, 0, 0);
        }
        __syncthreads();
    }

    int gslotbase = offs[e] + by * 128;
#pragma unroll
    for (int fm = 0; fm < 4; ++fm) {
        int feat = bx * 128 + wm + fm * 16 + g * 4;
        float4 bv = *(const float4*)(b1 + e * DFF + feat);
        float bb[4] = {bv.x, bv.y, bv.z, bv.w};
#pragma unroll
        for (int fn = 0; fn < 4; ++fn) {
            int sl = wn + fn * 16 + cl;
            if (by * 128 + sl < n_e) {
                half4v hv;
#pragma unroll
                for (int j = 0; j < 4; ++j) {
                    float vv = acc[fm][fn][j] + bb[j];
                    vv = 0.5f * vv * (1.f + erff(vv * 0.70710678118f));
                    hv[j] = (_Float16)vv;
                }
                *(half4v*)(H + (size_t)(gslotbase + sl) * DFF + feat) = hv;
            }
        }
    }
}

// GEMM2 (split-K=2): Y[kh][slot][D] = H @ W2 partial, A = W2t (d-major), B = H rows
__global__ __launch_bounds__(256, 4)
void k_ffn2(const _Float16* __restrict__ H, const _Float16* __restrict__ W2t,
            const int* __restrict__ counts, const int* __restrict__ offs,
            _Float16* __restrict__ Yh) {
    int e = blockIdx.z >> 1, kh = blockIdx.z & 1;
    int n_e = counts[e];
    int by = blockIdx.y;
    if (by * 128 >= n_e) return;
    int bx = blockIdx.x;

    __shared__ __align__(16) _Float16 As[128 * 64];
    __shared__ __align__(16) _Float16 Bs[128 * 64];

    int tid = threadIdx.x, lane = tid & 63, wid = tid >> 6;
    int srow = lane >> 3, u = lane & 7;
    int wm = (wid >> 1) * 64, wn = (wid & 1) * 64;
    int cl = lane & 15, g = lane >> 4;
    int v8 = u ^ srow;
    int rbase = wid * 32 + srow;

    int gslotbase = offs[e] + by * 128;
    const _Float16* Abase = W2t + (size_t)e * D * DFF + (size_t)(bx * 128) * DFF;
    const _Float16* Bbase = H + (size_t)gslotbase * DFF;

    f32x4 acc[4][4];
#pragma unroll
    for (int i = 0; i < 4; ++i)
#pragma unroll
        for (int j = 0; j < 4; ++j) acc[i][j] = (f32x4)0.f;

    int kt0 = kh * 2048, kt1 = kt0 + 2048;
    for (int kt = kt0; kt < kt1; kt += 64) {
#pragma unroll
        for (int i = 0; i < 4; ++i)
            GLOAD16(Abase + (size_t)(rbase + i * 8) * DFF + kt + v8 * 8, As + (wid * 4 + i) * 512);
#pragma unroll
        for (int i = 0; i < 4; ++i)
            GLOAD16(Bbase + (size_t)(rbase + i * 8) * DFF + kt + v8 * 8, Bs + (wid * 4 + i) * 512);
        __syncthreads();
#pragma unroll
        for (int ks = 0; ks < 2; ++ks) {
            half8v aF[4], bF[4];
            int vv = ((ks * 4 + g) ^ (cl & 7)) * 8;
#pragma unroll
            for (int fm = 0; fm < 4; ++fm)
                aF[fm] = *(const half8v*)(As + (wm + fm * 16 + cl) * 64 + vv);
#pragma unroll
            for (int fn = 0; fn < 4; ++fn)
                bF[fn] = *(const half8v*)(Bs + (wn + fn * 16 + cl) * 64 + vv);
#pragma unroll
            for (int fm = 0; fm < 4; ++fm)
#pragma unroll
                for (int fn = 0; fn < 4; ++fn)
                    acc[fm][fn] = __builtin_amdgcn_mfma_f32_16x16x32_f16(aF[fm], bF[fn], acc[fm][fn], 0, 0, 0);
        }
        __syncthreads();
    }

#pragma unroll
    for (int fm = 0; fm < 4; ++fm) {
        int d0 = bx * 128 + wm + fm * 16 + g * 4;
#pragma unroll
        for (int fn = 0; fn < 4; ++fn) {
            int sl = wn + fn * 16 + cl;
            half4v hv;
#pragma unroll
            for (int j = 0; j < 4; ++j) hv[j] = (_Float16)acc[fm][fn][j];
            *(half4v*)(Yh + ((size_t)kh * CAPTOT + gslotbase + sl) * D + d0) = hv;
        }
    }
}

__global__ void k_comb(const int* __restrict__ tk_e, const float* __restrict__ tk_w,
                       const int* __restrict__ tk_pos, const int* __restrict__ offs,
                       const _Float16* __restrict__ Yh, const float* __restrict__ b2,
                       float* __restrict__ out) {
    int idx = blockIdx.x * 256 + threadIdx.x;
    int t = idx >> 8;
    int d = (idx & 255) * 4;
    int e0 = tk_e[2 * t], e1 = tk_e[2 * t + 1];
    float w0 = tk_w[2 * t], w1 = tk_w[2 * t + 1];
    int s0 = offs[e0] + tk_pos[2 * t];
    int s1 = offs[e1] + tk_pos[2 * t + 1];
    half4v y00 = *(const half4v*)(Yh + (size_t)s0 * D + d);
    half4v y01 = *(const half4v*)(Yh + ((size_t)CAPTOT + s0) * D + d);
    half4v y10 = *(const half4v*)(Yh + (size_t)s1 * D + d);
    half4v y11 = *(const half4v*)(Yh + ((size_t)CAPTOT + s1) * D + d);
    float4 b20 = *(const float4*)(b2 + e0 * D + d);
    float4 b21 = *(const float4*)(b2 + e1 * D + d);
    float4 r;
    r.x = w0 * ((float)y00[0] + (float)y01[0] + b20.x) + w1 * ((float)y10[0] + (float)y11[0] + b21.x);
    r.y = w0 * ((float)y00[1] + (float)y01[1] + b20.y) + w1 * ((float)y10[1] + (float)y11[1] + b21.y);
    r.z = w0 * ((float)y00[2] + (float)y01[2] + b20.z) + w1 * ((float)y10[2] + (float)y11[2] + b21.z);
    r.w = w0 * ((float)y00[3] + (float)y01[3] + b20.w) + w1 * ((float)y10[3] + (float)y11[3] + b21.w);
    *(float4*)(out + (size_t)t * D + d) = r;
}

extern "C" void kernel_launch(void* const* d_in, const int* in_sizes, int n_in,
                              void* d_out, int out_size, void* d_ws, size_t ws_size,
                              hipStream_t stream) {
    const float* x  = (const float*)d_in[0];
    const float* W1 = (const float*)d_in[1];
    const float* b1 = (const float*)d_in[2];
    const float* W2 = (const float*)d_in[3];
    const float* b2 = (const float*)d_in[4];
    const float* Wg = (const float*)d_in[5];
    const float* bg = (const float*)d_in[6];
    float* out = (float*)d_out;

    char* ws = (char*)d_ws;
    int*   counts   = (int*)(ws);
    int*   offs     = (int*)(ws + 64);
    int*   tk_e     = (int*)(ws + 256);
    float* tk_w     = (float*)(ws + 33024);
    int*   tk_pos   = (int*)(ws + 65792);
    int*   tok_list = (int*)(ws + 98560);
    _Float16* xh    = (_Float16*)(ws + (1u << 20));
    _Float16* W1t   = (_Float16*)(ws + (10u << 20));
    _Float16* Yh    = (_Float16*)(ws + (10u << 20));       // overlays W1t after ffn1
    _Float16* W2t   = (_Float16*)(ws + (78u << 20));
    _Float16* H     = (_Float16*)(ws + (146u << 20));

    hipMemsetAsync(counts, 0, 64, stream);
    k_gate<<<TOK / 4, 256, 0, stream>>>(x, Wg, bg, counts, tk_e, tk_w, tk_pos, tok_list);
    k_prep<<<1, 1, 0, stream>>>(counts, offs);
    k_cvt_x<<<(TOK * D / 8) / 256, 256, 0, stream>>>(x, xh);
    k_tr<<<dim3(DFF / 64, D / 64, NE), 256, 0, stream>>>(W1, W1t, D, DFF);
    k_tr<<<dim3(D / 64, DFF / 64, NE), 256, 0, stream>>>(W2, W2t, DFF, D);
    k_ffn1<<<dim3(DFF / 128, 32, NE), 256, 0, stream>>>(xh, W1t, b1, counts, offs, tok_list, H);
    k_ffn2<<<dim3(D / 128, 32, NE * 2), 256, 0, stream>>>(H, W2t, counts, offs, Yh);
    k_comb<<<(TOK * D / 4) / 256, 256, 0, stream>>>(tk_e, tk_w, tk_pos, offs, Yh, b2, out);
}